// Round 13
// baseline (521.179 us; speedup 1.0000x reference)
//
#include <hip/hip_runtime.h>
#include <hip/hip_fp16.h>
#include <math.h>

#define NNODE 100000
#define NEDGE 1600000
#define FIN   128
#define AGG   48
#define FCH   192
#define NCLS  10
#define SLOPE 0.2f
#define L2E   1.44269504088896340736f

#define NBUCK 391     // ceil(NNODE/256) coarse dst-buckets (256 nodes each)
#define BCAP  4992    // bucket capacity: mean 4096, sigma 64 -> +14 sigma
#define EPB   2048    // edges per binA block

// fp16 pack/unpack helpers
__device__ __forceinline__ float2 h2f(int p) {
    union { int i; __half2 h; } u; u.i = p;
    return __half22float2(u.h);
}
__device__ __forceinline__ int f2h(float a, float b) {
    union { __half2 h; int i; } u;
    u.h = __floats2half2_rn(a, b);
    return u.i;
}

// ---------------- CSR build (two-level counting sort, no node histogram) ----

// Pass A, LDS-staged: bin 2048 edges into coarse buckets; records staged in
// LDS grouped by bucket, written out linearly (coalesced runs). No per-node
// atomics (R8: 1.6M atomics into 400KB was a ~100us wall).
__global__ __launch_bounds__(256) void binA_kernel(const int* __restrict__ ei,
                                                   const float4* __restrict__ ea,
                                                   int* __restrict__ bcnt,
                                                   int4* __restrict__ bbuf) {
    __shared__ int  hist[NBUCK];
    __shared__ int  lofs[NBUCK];     // exclusive scan of hist (block-local)
    __shared__ int  gbase[NBUCK];    // reserved global base within bucket
    __shared__ int  scA[512], scB[512];
    __shared__ int  gidx[EPB];       // per-slot global bbuf index (-1 = drop)
    __shared__ int4 stage[EPB];

    const int t = threadIdx.x;
    const int wgbase = blockIdx.x * EPB;
    const int nvalid = min(EPB, NEDGE - wgbase);

    for (int i = t; i < NBUCK; i += 256) hist[i] = 0;
    __syncthreads();

    int d[8], rank[8];
#pragma unroll
    for (int i = 0; i < 8; ++i) {
        int e = wgbase + i * 256 + t;
        if (e < NEDGE) {
            d[i] = ei[NEDGE + e];
            rank[i] = atomicAdd(&hist[d[i] >> 8], 1);
        } else d[i] = -1;
    }
    __syncthreads();

    // Hillis-Steele inclusive scan of hist (padded to 512), ping-pong A->B
    {
        scA[t] = (t < NBUCK) ? hist[t] : 0;
        scA[t + 256] = (t + 256 < NBUCK) ? hist[t + 256] : 0;
        __syncthreads();
        int* src = scA; int* dst = scB;
#pragma unroll
        for (int o = 1; o < 512; o <<= 1) {
            int i0 = t, i1 = t + 256;
            int v0 = src[i0] + ((i0 >= o) ? src[i0 - o] : 0);
            int v1 = src[i1] + ((i1 >= o) ? src[i1 - o] : 0);
            __syncthreads();
            dst[i0] = v0; dst[i1] = v1;
            __syncthreads();
            int* tmp = src; src = dst; dst = tmp;
        }
        if (t < NBUCK) lofs[t] = src[t] - hist[t];
        if (t + 256 < NBUCK) lofs[t + 256] = src[t + 256] - hist[t + 256];
    }
    for (int i = t; i < NBUCK; i += 256)
        gbase[i] = hist[i] ? atomicAdd(&bcnt[i], hist[i]) : 0;
    __syncthreads();

#pragma unroll
    for (int i = 0; i < 8; ++i) {
        int e = wgbase + i * 256 + t;
        if (e < NEDGE) {
            int b = d[i] >> 8;
            int slot = lofs[b] + rank[i];
            int gp = gbase[b] + rank[i];
            float4 v = ea[e];
            stage[slot] = make_int4(ei[e], d[i], f2h(v.x, v.y), f2h(v.z, v.w));
            gidx[slot] = (gp < BCAP) ? (b * BCAP + gp) : -1;
        }
    }
    __syncthreads();

    for (int i = t; i < nvalid; i += 256) {
        int gi = gidx[i];
        if (gi >= 0) bbuf[gi] = stage[i];
    }
}

// exclusive scan of the 391 bucket totals (single block)
__global__ void bscan_kernel(const int* __restrict__ bcnt, int* __restrict__ bstart,
                             int* __restrict__ starts) {
    __shared__ int s[512];
    int t = threadIdx.x;
    int v = (t < NBUCK) ? bcnt[t] : 0;
    s[t] = v;
    __syncthreads();
    int acc = v;
    for (int o = 1; o < 512; o <<= 1) {
        int x = (t >= o) ? s[t - o] : 0;
        __syncthreads();
        acc += x;
        s[t] = acc;
        __syncthreads();
    }
    if (t < NBUCK) bstart[t] = acc - v;
    if (t == 0) starts[NNODE] = NEDGE;
}

// Pass B: one workgroup (1024 threads) per coarse bucket; per-node LDS count
// + scan -> starts[]; exact-slot scatter into the bucket's contiguous span.
__global__ __launch_bounds__(1024) void binB_kernel(const int* __restrict__ bcnt,
                                                    const int* __restrict__ bstart,
                                                    const int4* __restrict__ bbuf,
                                                    int* __restrict__ starts,
                                                    int4* __restrict__ edges) {
    __shared__ int ncnt[256];
    __shared__ int sc[256];
    __shared__ int lcur[256];
    const int b = blockIdx.x;
    const int t = threadIdx.x;
    if (t < 256) ncnt[t] = 0;
    __syncthreads();
    int cnt = min(bcnt[b], BCAP);
    int base = bstart[b];
    for (int i = t; i < cnt; i += 1024)
        atomicAdd(&ncnt[bbuf[(size_t)b * BCAP + i].y & 255], 1);
    __syncthreads();
    int v = 0, acc = 0;
    if (t < 256) { v = ncnt[t]; sc[t] = v; }
    __syncthreads();
    acc = v;
    for (int o = 1; o < 256; o <<= 1) {
        int x = 0;
        if (t < 256 && t >= o) x = sc[t - o];
        __syncthreads();
        if (t < 256) { acc += x; sc[t] = acc; }
        __syncthreads();
    }
    if (t < 256) {
        int node = (b << 8) + t;
        int st = base + acc - v;      // exclusive
        lcur[t] = st;
        if (node < NNODE) starts[node] = st;
    }
    __syncthreads();
    for (int i = t; i < cnt; i += 1024) {
        int4 rec = bbuf[(size_t)b * BCAP + i];
        int pos = atomicAdd(&lcur[rec.y & 255], 1);
        edges[pos] = make_int4(rec.x, rec.z, rec.w, 0);
    }
}

// ---------------- per-layer kernels ----------------

// LDS-tiled dual GEMM, conflict-free layouts (R9 fix). xl written packed
// fp16, row padded to 64 halfs (128B) -> one cache line per gather; xr fp32.
template <int K, int KT>
__global__ __launch_bounds__(192) void transform_tiled(
    const float* __restrict__ h,
    const float* __restrict__ Wl, const float* __restrict__ bl,
    const float* __restrict__ Wr, const float* __restrict__ br,
    __half* __restrict__ xlh, float* __restrict__ xr)
{
    constexpr int NT = 48;
    constexpr int KP = K + 4;
    __shared__ float sW[2][KT * 48];     // [m][j*48+k] = W^T tile
    __shared__ float sH[NT * KP];

    const int t = threadIdx.x;
    const int base = blockIdx.x * NT;

    for (int p = t; p < NT * (K / 4); p += 192) {
        int row = p / (K / 4);
        int c4  = p - row * (K / 4);
        int gn  = base + row;
        float4 v = (gn < NNODE) ? ((const float4*)h)[(size_t)gn * (K / 4) + c4]
                                : make_float4(0.f, 0.f, 0.f, 0.f);
        ((float4*)(sH + row * KP))[c4] = v;
    }

    const int q  = t % 12;
    const int ng = t / 12;
    float al[3][4] = {};
    float ar[3][4] = {};

    const float4* Wl4 = (const float4*)Wl;
    const float4* Wr4 = (const float4*)Wr;

    for (int j0 = 0; j0 < K; j0 += KT) {
        __syncthreads();
        for (int p = t; p < 48 * (KT / 4); p += 192) {
            int k  = p % 48;
            int jq = p / 48;
            float4 wl = Wl4[(size_t)k * (K / 4) + (j0 / 4) + jq];
            float4 wr = Wr4[(size_t)k * (K / 4) + (j0 / 4) + jq];
            int j = jq * 4;
            sW[0][(j + 0) * 48 + k] = wl.x; sW[0][(j + 1) * 48 + k] = wl.y;
            sW[0][(j + 2) * 48 + k] = wl.z; sW[0][(j + 3) * 48 + k] = wl.w;
            sW[1][(j + 0) * 48 + k] = wr.x; sW[1][(j + 1) * 48 + k] = wr.y;
            sW[1][(j + 2) * 48 + k] = wr.z; sW[1][(j + 3) * 48 + k] = wr.w;
        }
        __syncthreads();

        const float4* sWl4 = (const float4*)sW[0];
        const float4* sWr4 = (const float4*)sW[1];
        const float* sHj = sH + j0;
#pragma unroll 4
        for (int j = 0; j < KT; ++j) {
            float4 wl4 = sWl4[j * 12 + q];
            float4 wr4 = sWr4[j * 12 + q];
            float h0 = sHj[(ng + 0)  * KP + j];
            float h1 = sHj[(ng + 16) * KP + j];
            float h2 = sHj[(ng + 32) * KP + j];
            al[0][0] += h0 * wl4.x; al[0][1] += h0 * wl4.y; al[0][2] += h0 * wl4.z; al[0][3] += h0 * wl4.w;
            ar[0][0] += h0 * wr4.x; ar[0][1] += h0 * wr4.y; ar[0][2] += h0 * wr4.z; ar[0][3] += h0 * wr4.w;
            al[1][0] += h1 * wl4.x; al[1][1] += h1 * wl4.y; al[1][2] += h1 * wl4.z; al[1][3] += h1 * wl4.w;
            ar[1][0] += h1 * wr4.x; ar[1][1] += h1 * wr4.y; ar[1][2] += h1 * wr4.z; ar[1][3] += h1 * wr4.w;
            al[2][0] += h2 * wl4.x; al[2][1] += h2 * wl4.y; al[2][2] += h2 * wl4.z; al[2][3] += h2 * wl4.w;
            ar[2][0] += h2 * wr4.x; ar[2][1] += h2 * wr4.y; ar[2][2] += h2 * wr4.z; ar[2][3] += h2 * wr4.w;
        }
    }

    float4 bl4 = ((const float4*)bl)[q];
    float4 br4 = ((const float4*)br)[q];
#pragma unroll
    for (int i = 0; i < 3; ++i) {
        int gn = base + ng + 16 * i;
        if (gn < NNODE) {
            int2 pk = make_int2(f2h(al[i][0] + bl4.x, al[i][1] + bl4.y),
                                f2h(al[i][2] + bl4.z, al[i][3] + bl4.w));
            ((int2*)xlh)[(size_t)gn * 16 + q] = pk;
            float4 orr = make_float4(ar[i][0] + br4.x, ar[i][1] + br4.y,
                                     ar[i][2] + br4.z, ar[i][3] + br4.w);
            ((float4*)xr)[(size_t)gn * 12 + q] = orr;
        }
    }
}

// sum within each 16-lane group (pure-VALU DPP butterfly, broadcast to all 16)
__device__ __forceinline__ float group_sum16(float v) {
#define DPP_ADD(ctrl)                                                          \
    v += __int_as_float(__builtin_amdgcn_update_dpp(                           \
        0, __float_as_int(v), ctrl, 0xf, 0xf, true))
    DPP_ADD(0xB1);    // lane ^ 1
    DPP_ADD(0x4E);    // lane ^ 2
    DPP_ADD(0x141);   // lane ^ 7
    DPP_ADD(0x140);   // lane ^ 15
#undef DPP_ADD
    return v;
}

// fused edge attention + segment softmax (fixed max=0) + aggregation.
// One wave per node; 8 edges/iteration (2 per 16-lane slot) for gather MLP.
// att-dot uses the identity a*lrelu(x) = (0.6a)x + (0.4a)|x| (exact for
// slope 0.2): 2 FMAs/channel with free |x| VOP3 modifiers, replacing the
// 4-op max/min/fma/fma sequence (R10: VALUBusy 82%, issue-bound).
__global__ void aggregate_kernel(const __half* __restrict__ xlh, const float* __restrict__ xr,
                                 const int* __restrict__ starts, const int4* __restrict__ edges,
                                 const float* __restrict__ We, const float* __restrict__ att,
                                 const float* __restrict__ bias,
                                 float* __restrict__ hout) {
    int node = (blockIdx.x * blockDim.x + threadIdx.x) >> 6;
    if (node >= NNODE) return;
    const int lane = threadIdx.x & 63;
    const int g = lane >> 4;          // edge slot within chunk (0..3)
    const int r = lane & 15;          // channel quad; active if r < 12
    const bool act = r < 12;
    const int rc = act ? r : 0;
    const int c0 = 4 * rc;

    const float4* We4 = (const float4*)We;
    float4 w0 = We4[4 * rc + 0], w1 = We4[4 * rc + 1],
           w2 = We4[4 * rc + 2], w3 = We4[4 * rc + 3];
    // c1 = 0.6*a*log2e (x-coeff), c2 = 0.4*a*log2e (|x|-coeff); 0 on idle lanes
    float c1A = act ? att[c0 + 0] * (L2E * 0.6f) : 0.f;
    float c2A = act ? att[c0 + 0] * (L2E * 0.4f) : 0.f;
    float c1B = act ? att[c0 + 1] * (L2E * 0.6f) : 0.f;
    float c2B = act ? att[c0 + 1] * (L2E * 0.4f) : 0.f;
    float c1C = act ? att[c0 + 2] * (L2E * 0.6f) : 0.f;
    float c2C = act ? att[c0 + 2] * (L2E * 0.4f) : 0.f;
    float c1D = act ? att[c0 + 3] * (L2E * 0.6f) : 0.f;
    float c2D = act ? att[c0 + 3] * (L2E * 0.4f) : 0.f;
    float4 xr4 = ((const float4*)xr)[(size_t)node * 12 + rc];

    int s = starts[node];
    int e_end = starts[node + 1];
    float den = 0.f, ac0 = 0.f, ac1 = 0.f, ac2 = 0.f, ac3 = 0.f;

    for (int j = s; j < e_end; j += 8) {
        int j0 = j + g, j1 = j + 4 + g;
        bool v0 = j0 < e_end, v1 = j1 < e_end;
        int4 edA = edges[v0 ? j0 : j];
        int4 edB = edges[v1 ? j1 : j];
        int2 xiA = ((const int2*)xlh)[(size_t)edA.x * 16 + rc];
        int2 xiB = ((const int2*)xlh)[(size_t)edB.x * 16 + rc];

        float2 eA01 = h2f(edA.y), eA23 = h2f(edA.z);
        float2 eB01 = h2f(edB.y), eB23 = h2f(edB.z);
        float2 xA01 = h2f(xiA.x), xA23 = h2f(xiA.y);
        float2 xB01 = h2f(xiB.x), xB23 = h2f(xiB.y);

        float vA0 = fmaf(w0.w, eA23.y, fmaf(w0.z, eA23.x, fmaf(w0.y, eA01.y, fmaf(w0.x, eA01.x, xA01.x + xr4.x))));
        float vA1 = fmaf(w1.w, eA23.y, fmaf(w1.z, eA23.x, fmaf(w1.y, eA01.y, fmaf(w1.x, eA01.x, xA01.y + xr4.y))));
        float vA2 = fmaf(w2.w, eA23.y, fmaf(w2.z, eA23.x, fmaf(w2.y, eA01.y, fmaf(w2.x, eA01.x, xA23.x + xr4.z))));
        float vA3 = fmaf(w3.w, eA23.y, fmaf(w3.z, eA23.x, fmaf(w3.y, eA01.y, fmaf(w3.x, eA01.x, xA23.y + xr4.w))));
        float vB0 = fmaf(w0.w, eB23.y, fmaf(w0.z, eB23.x, fmaf(w0.y, eB01.y, fmaf(w0.x, eB01.x, xB01.x + xr4.x))));
        float vB1 = fmaf(w1.w, eB23.y, fmaf(w1.z, eB23.x, fmaf(w1.y, eB01.y, fmaf(w1.x, eB01.x, xB01.y + xr4.y))));
        float vB2 = fmaf(w2.w, eB23.y, fmaf(w2.z, eB23.x, fmaf(w2.y, eB01.y, fmaf(w2.x, eB01.x, xB23.x + xr4.z))));
        float vB3 = fmaf(w3.w, eB23.y, fmaf(w3.z, eB23.x, fmaf(w3.y, eB01.y, fmaf(w3.x, eB01.x, xB23.y + xr4.w))));

        // t = sum_k (0.6 a_k) v_k + (0.4 a_k) |v_k|   (|v| = free modifier)
        float tA;
        tA =            c1A * vA0 + c2A * fabsf(vA0);
        tA = fmaf(c1B, vA1, fmaf(c2B, fabsf(vA1), tA));
        tA = fmaf(c1C, vA2, fmaf(c2C, fabsf(vA2), tA));
        tA = fmaf(c1D, vA3, fmaf(c2D, fabsf(vA3), tA));
        float tB;
        tB =            c1A * vB0 + c2A * fabsf(vB0);
        tB = fmaf(c1B, vB1, fmaf(c2B, fabsf(vB1), tB));
        tB = fmaf(c1C, vB2, fmaf(c2C, fabsf(vB2), tB));
        tB = fmaf(c1D, vB3, fmaf(c2D, fabsf(vB3), tB));

        tA = group_sum16(tA);
        tB = group_sum16(tB);

        float pA = v0 ? exp2f(tA) : 0.f;
        float pB = v1 ? exp2f(tB) : 0.f;
        den += pA + pB;
        ac0 = fmaf(pB, xB01.x, fmaf(pA, xA01.x, ac0));
        ac1 = fmaf(pB, xB01.y, fmaf(pA, xA01.y, ac1));
        ac2 = fmaf(pB, xB23.x, fmaf(pA, xA23.x, ac2));
        ac3 = fmaf(pB, xB23.y, fmaf(pA, xA23.y, ac3));
    }

    // cross-group reduction: bit4 (xor16) then bit5 (xor32)
    den += __int_as_float(__builtin_amdgcn_ds_swizzle(__float_as_int(den), 0x401F));
    ac0 += __int_as_float(__builtin_amdgcn_ds_swizzle(__float_as_int(ac0), 0x401F));
    ac1 += __int_as_float(__builtin_amdgcn_ds_swizzle(__float_as_int(ac1), 0x401F));
    ac2 += __int_as_float(__builtin_amdgcn_ds_swizzle(__float_as_int(ac2), 0x401F));
    ac3 += __int_as_float(__builtin_amdgcn_ds_swizzle(__float_as_int(ac3), 0x401F));
    den += __shfl_xor(den, 32);
    ac0 += __shfl_xor(ac0, 32);
    ac1 += __shfl_xor(ac1, 32);
    ac2 += __shfl_xor(ac2, 32);
    ac3 += __shfl_xor(ac3, 32);

    if (lane < 16 && act) {
        float inv = 1.f / fmaxf(den, 1e-16f);
        float4 b4 = ((const float4*)bias)[r];
        float4 o = make_float4(fmaxf(fmaf(ac0, inv, b4.x), 0.f),
                               fmaxf(fmaf(ac1, inv, b4.y), 0.f),
                               fmaxf(fmaf(ac2, inv, b4.z), 0.f),
                               fmaxf(fmaf(ac3, inv, b4.w), 0.f));
        ((float4*)hout)[(size_t)node * 12 + r] = o;
    }
}

// ---------------- readout + head ----------------

__global__ void readout_kernel(const float* __restrict__ h, float* __restrict__ g) {
    int wid = (blockIdx.x * blockDim.x + threadIdx.x) >> 6;
    int lane = threadIdx.x & 63;
    int nw = (gridDim.x * blockDim.x) >> 6;
    if (lane < AGG) {
        float acc = 0.f;
        for (int n = wid; n < NNODE; n += nw) acc += h[n * AGG + lane];
        atomicAdd(&g[lane], acc);
    }
}

__global__ void head_kernel(const float* __restrict__ g,
                            const float* __restrict__ fc1w, const float* __restrict__ fc1b,
                            const float* __restrict__ fc2w, const float* __restrict__ fc2b,
                            float* __restrict__ out) {
    __shared__ float sg[AGG];
    __shared__ float s1[FCH];
    __shared__ float s2[NCLS];
    int t = threadIdx.x;
    if (t < AGG) sg[t] = g[t];
    __syncthreads();
    if (t < FCH) {
        float a = fc1b[t];
        for (int j = 0; j < AGG; ++j) a += fc1w[t * AGG + j] * sg[j];
        s1[t] = fmaxf(a, 0.f);
    }
    __syncthreads();
    if (t < NCLS) {
        float a = fc2b[t];
        for (int j = 0; j < FCH; ++j) a += fc2w[t * FCH + j] * s1[j];
        s2[t] = a;
    }
    __syncthreads();
    if (t == 0) {
        float mx = s2[0];
        for (int i = 1; i < NCLS; ++i) mx = fmaxf(mx, s2[i]);
        float ex[NCLS];
        float den = 0.f;
        for (int i = 0; i < NCLS; ++i) { ex[i] = __expf(s2[i] - mx); den += ex[i]; }
        for (int i = 0; i < NCLS; ++i) out[i] = ex[i] / den;
    }
}

// ---------------- launch ----------------

extern "C" void kernel_launch(void* const* d_in, const int* in_sizes, int n_in,
                              void* d_out, int out_size, void* d_ws, size_t ws_size,
                              hipStream_t stream) {
    const float* x  = (const float*)d_in[0];
    const int*   ei = (const int*)d_in[1];
    const float* ea = (const float*)d_in[2];
    const float* Wl[3], *bl[3], *Wr[3], *br[3], *We[3], *att[3], *bb[3];
    for (int l = 0; l < 3; ++l) {
        int base = 3 + l * 7;
        Wl[l]  = (const float*)d_in[base + 0];
        bl[l]  = (const float*)d_in[base + 1];
        Wr[l]  = (const float*)d_in[base + 2];
        br[l]  = (const float*)d_in[base + 3];
        We[l]  = (const float*)d_in[base + 4];
        att[l] = (const float*)d_in[base + 5];
        bb[l]  = (const float*)d_in[base + 6];
    }
    const float* fc1w = (const float*)d_in[24];
    const float* fc1b = (const float*)d_in[25];
    const float* fc2w = (const float*)d_in[26];
    const float* fc2b = (const float*)d_in[27];
    float* outp = (float*)d_out;

    char* ws = (char*)d_ws;
    // region0 (32.0 MB): xlh (12.8 MB) + xr (19.2 MB); ALIASED by bbuf
    // (31.3 MB) whose lifetime (binA->binB) ends before transform writes.
    __half* xlh   = (__half*)ws;
    float*  xr    = (float*)(ws + (size_t)NNODE * 64 * 2);
    int4*   bbuf  = (int4*)ws;
    size_t off = (size_t)NNODE * 64 * 2 + (size_t)NNODE * AGG * 4;
    auto take = [&](size_t bytes) -> void* {
        void* p = ws + off;
        off = (off + bytes + 255) & ~(size_t)255;
        return p;
    };
    float*  h      = (float*)take((size_t)NNODE * AGG * 4);
    int*    starts = (int*)take((size_t)(NNODE + 1) * 4);
    int*    bcnt   = (int*)take(NBUCK * 4);
    int*    bstart = (int*)take((NBUCK + 1) * 4);
    int4*   edges  = (int4*)take((size_t)NEDGE * 16);
    float*  g      = (float*)take(64 * 4);

    // CSR build: binA (bucket bins) -> bucket scan -> binB (per-node count +
    // starts + exact CSR scatter)
    hipMemsetAsync(bcnt, 0, NBUCK * 4, stream);
    binA_kernel<<<(NEDGE + EPB - 1) / EPB, 256, 0, stream>>>(ei, (const float4*)ea,
                                                             bcnt, bbuf);
    bscan_kernel<<<1, 512, 0, stream>>>(bcnt, bstart, starts);
    binB_kernel<<<NBUCK, 1024, 0, stream>>>(bcnt, bstart, bbuf, starts, edges);

    const int TGRID = (NNODE + 47) / 48;
    const int AGRID = (NNODE + 3) / 4;

    transform_tiled<FIN, 64><<<TGRID, 192, 0, stream>>>(x, Wl[0], bl[0], Wr[0], br[0], xlh, xr);
    aggregate_kernel<<<AGRID, 256, 0, stream>>>(xlh, xr, starts, edges,
                                                We[0], att[0], bb[0], h);
    transform_tiled<AGG, 48><<<TGRID, 192, 0, stream>>>(h, Wl[1], bl[1], Wr[1], br[1], xlh, xr);
    aggregate_kernel<<<AGRID, 256, 0, stream>>>(xlh, xr, starts, edges,
                                                We[1], att[1], bb[1], h);
    transform_tiled<AGG, 48><<<TGRID, 192, 0, stream>>>(h, Wl[2], bl[2], Wr[2], br[2], xlh, xr);
    aggregate_kernel<<<AGRID, 256, 0, stream>>>(xlh, xr, starts, edges,
                                                We[2], att[2], bb[2], h);

    hipMemsetAsync(g, 0, 64 * 4, stream);
    readout_kernel<<<256, 256, 0, stream>>>(h, g);
    head_kernel<<<1, 192, 0, stream>>>(g, fc1w, fc1b, fc2w, fc2b, outp);
}

// Round 14
// 428.801 us; speedup vs baseline: 1.2154x; 1.2154x over previous
//
#include <hip/hip_runtime.h>
#include <hip/hip_fp16.h>
#include <math.h>

#define NNODE 100000
#define NEDGE 1600000
#define FIN   128
#define AGG   48
#define FCH   192
#define NCLS  10
#define SLOPE 0.2f
#define L2E   1.44269504088896340736f

#define NBUCK 391     // ceil(NNODE/256) coarse dst-buckets (256 nodes each)
#define BCAP  4992    // bucket capacity: mean 4096, sigma 64 -> +14 sigma
#define EPB   2048    // edges per binA block

// fp16 pack/unpack helpers
__device__ __forceinline__ float2 h2f(int p) {
    union { int i; __half2 h; } u; u.i = p;
    return __half22float2(u.h);
}
__device__ __forceinline__ int f2h(float a, float b) {
    union { __half2 h; int i; } u;
    u.h = __floats2half2_rn(a, b);
    return u.i;
}

// ---------------- CSR build (two-level counting sort, no node histogram) ----

// Pass A, LDS-staged: bin 2048 edges into coarse buckets; records staged in
// LDS grouped by bucket, written out linearly (coalesced runs). No per-node
// atomics (R8: 1.6M atomics into 400KB was a ~100us wall).
__global__ __launch_bounds__(256) void binA_kernel(const int* __restrict__ ei,
                                                   const float4* __restrict__ ea,
                                                   int* __restrict__ bcnt,
                                                   int4* __restrict__ bbuf) {
    __shared__ int  hist[NBUCK];
    __shared__ int  lofs[NBUCK];     // exclusive scan of hist (block-local)
    __shared__ int  gbase[NBUCK];    // reserved global base within bucket
    __shared__ int  scA[512], scB[512];
    __shared__ int  gidx[EPB];       // per-slot global bbuf index (-1 = drop)
    __shared__ int4 stage[EPB];

    const int t = threadIdx.x;
    const int wgbase = blockIdx.x * EPB;
    const int nvalid = min(EPB, NEDGE - wgbase);

    for (int i = t; i < NBUCK; i += 256) hist[i] = 0;
    __syncthreads();

    int d[8], rank[8];
#pragma unroll
    for (int i = 0; i < 8; ++i) {
        int e = wgbase + i * 256 + t;
        if (e < NEDGE) {
            d[i] = ei[NEDGE + e];
            rank[i] = atomicAdd(&hist[d[i] >> 8], 1);
        } else d[i] = -1;
    }
    __syncthreads();

    // Hillis-Steele inclusive scan of hist (padded to 512), ping-pong A->B
    {
        scA[t] = (t < NBUCK) ? hist[t] : 0;
        scA[t + 256] = (t + 256 < NBUCK) ? hist[t + 256] : 0;
        __syncthreads();
        int* src = scA; int* dst = scB;
#pragma unroll
        for (int o = 1; o < 512; o <<= 1) {
            int i0 = t, i1 = t + 256;
            int v0 = src[i0] + ((i0 >= o) ? src[i0 - o] : 0);
            int v1 = src[i1] + ((i1 >= o) ? src[i1 - o] : 0);
            __syncthreads();
            dst[i0] = v0; dst[i1] = v1;
            __syncthreads();
            int* tmp = src; src = dst; dst = tmp;
        }
        if (t < NBUCK) lofs[t] = src[t] - hist[t];
        if (t + 256 < NBUCK) lofs[t + 256] = src[t + 256] - hist[t + 256];
    }
    for (int i = t; i < NBUCK; i += 256)
        gbase[i] = hist[i] ? atomicAdd(&bcnt[i], hist[i]) : 0;
    __syncthreads();

#pragma unroll
    for (int i = 0; i < 8; ++i) {
        int e = wgbase + i * 256 + t;
        if (e < NEDGE) {
            int b = d[i] >> 8;
            int slot = lofs[b] + rank[i];
            int gp = gbase[b] + rank[i];
            float4 v = ea[e];
            stage[slot] = make_int4(ei[e], d[i], f2h(v.x, v.y), f2h(v.z, v.w));
            gidx[slot] = (gp < BCAP) ? (b * BCAP + gp) : -1;
        }
    }
    __syncthreads();

    for (int i = t; i < nvalid; i += 256) {
        int gi = gidx[i];
        if (gi >= 0) bbuf[gi] = stage[i];
    }
}

// exclusive scan of the 391 bucket totals (single block)
__global__ void bscan_kernel(const int* __restrict__ bcnt, int* __restrict__ bstart,
                             int* __restrict__ starts) {
    __shared__ int s[512];
    int t = threadIdx.x;
    int v = (t < NBUCK) ? bcnt[t] : 0;
    s[t] = v;
    __syncthreads();
    int acc = v;
    for (int o = 1; o < 512; o <<= 1) {
        int x = (t >= o) ? s[t - o] : 0;
        __syncthreads();
        acc += x;
        s[t] = acc;
        __syncthreads();
    }
    if (t < NBUCK) bstart[t] = acc - v;
    if (t == 0) starts[NNODE] = NEDGE;
}

// Pass B: one workgroup (1024 threads) per coarse bucket; per-node LDS count
// + scan -> starts[]; exact-slot scatter into the bucket's contiguous span.
__global__ __launch_bounds__(1024) void binB_kernel(const int* __restrict__ bcnt,
                                                    const int* __restrict__ bstart,
                                                    const int4* __restrict__ bbuf,
                                                    int* __restrict__ starts,
                                                    int4* __restrict__ edges) {
    __shared__ int ncnt[256];
    __shared__ int sc[256];
    __shared__ int lcur[256];
    const int b = blockIdx.x;
    const int t = threadIdx.x;
    if (t < 256) ncnt[t] = 0;
    __syncthreads();
    int cnt = min(bcnt[b], BCAP);
    int base = bstart[b];
    for (int i = t; i < cnt; i += 1024)
        atomicAdd(&ncnt[bbuf[(size_t)b * BCAP + i].y & 255], 1);
    __syncthreads();
    int v = 0, acc = 0;
    if (t < 256) { v = ncnt[t]; sc[t] = v; }
    __syncthreads();
    acc = v;
    for (int o = 1; o < 256; o <<= 1) {
        int x = 0;
        if (t < 256 && t >= o) x = sc[t - o];
        __syncthreads();
        if (t < 256) { acc += x; sc[t] = acc; }
        __syncthreads();
    }
    if (t < 256) {
        int node = (b << 8) + t;
        int st = base + acc - v;      // exclusive
        lcur[t] = st;
        if (node < NNODE) starts[node] = st;
    }
    __syncthreads();
    for (int i = t; i < cnt; i += 1024) {
        int4 rec = bbuf[(size_t)b * BCAP + i];
        int pos = atomicAdd(&lcur[rec.y & 255], 1);
        edges[pos] = make_int4(rec.x, rec.z, rec.w, 0);
    }
}

// ---------------- per-layer kernels ----------------

// LDS-tiled dual GEMM, conflict-free layouts (R9 fix). xl written packed
// fp16, row padded to 64 halfs (128B) -> one cache line per gather; xr fp32.
template <int K, int KT>
__global__ __launch_bounds__(192) void transform_tiled(
    const float* __restrict__ h,
    const float* __restrict__ Wl, const float* __restrict__ bl,
    const float* __restrict__ Wr, const float* __restrict__ br,
    __half* __restrict__ xlh, float* __restrict__ xr)
{
    constexpr int NT = 48;
    constexpr int KP = K + 4;
    __shared__ float sW[2][KT * 48];     // [m][j*48+k] = W^T tile
    __shared__ float sH[NT * KP];

    const int t = threadIdx.x;
    const int base = blockIdx.x * NT;

    for (int p = t; p < NT * (K / 4); p += 192) {
        int row = p / (K / 4);
        int c4  = p - row * (K / 4);
        int gn  = base + row;
        float4 v = (gn < NNODE) ? ((const float4*)h)[(size_t)gn * (K / 4) + c4]
                                : make_float4(0.f, 0.f, 0.f, 0.f);
        ((float4*)(sH + row * KP))[c4] = v;
    }

    const int q  = t % 12;
    const int ng = t / 12;
    float al[3][4] = {};
    float ar[3][4] = {};

    const float4* Wl4 = (const float4*)Wl;
    const float4* Wr4 = (const float4*)Wr;

    for (int j0 = 0; j0 < K; j0 += KT) {
        __syncthreads();
        for (int p = t; p < 48 * (KT / 4); p += 192) {
            int k  = p % 48;
            int jq = p / 48;
            float4 wl = Wl4[(size_t)k * (K / 4) + (j0 / 4) + jq];
            float4 wr = Wr4[(size_t)k * (K / 4) + (j0 / 4) + jq];
            int j = jq * 4;
            sW[0][(j + 0) * 48 + k] = wl.x; sW[0][(j + 1) * 48 + k] = wl.y;
            sW[0][(j + 2) * 48 + k] = wl.z; sW[0][(j + 3) * 48 + k] = wl.w;
            sW[1][(j + 0) * 48 + k] = wr.x; sW[1][(j + 1) * 48 + k] = wr.y;
            sW[1][(j + 2) * 48 + k] = wr.z; sW[1][(j + 3) * 48 + k] = wr.w;
        }
        __syncthreads();

        const float4* sWl4 = (const float4*)sW[0];
        const float4* sWr4 = (const float4*)sW[1];
        const float* sHj = sH + j0;
#pragma unroll 4
        for (int j = 0; j < KT; ++j) {
            float4 wl4 = sWl4[j * 12 + q];
            float4 wr4 = sWr4[j * 12 + q];
            float h0 = sHj[(ng + 0)  * KP + j];
            float h1 = sHj[(ng + 16) * KP + j];
            float h2 = sHj[(ng + 32) * KP + j];
            al[0][0] += h0 * wl4.x; al[0][1] += h0 * wl4.y; al[0][2] += h0 * wl4.z; al[0][3] += h0 * wl4.w;
            ar[0][0] += h0 * wr4.x; ar[0][1] += h0 * wr4.y; ar[0][2] += h0 * wr4.z; ar[0][3] += h0 * wr4.w;
            al[1][0] += h1 * wl4.x; al[1][1] += h1 * wl4.y; al[1][2] += h1 * wl4.z; al[1][3] += h1 * wl4.w;
            ar[1][0] += h1 * wr4.x; ar[1][1] += h1 * wr4.y; ar[1][2] += h1 * wr4.z; ar[1][3] += h1 * wr4.w;
            al[2][0] += h2 * wl4.x; al[2][1] += h2 * wl4.y; al[2][2] += h2 * wl4.z; al[2][3] += h2 * wl4.w;
            ar[2][0] += h2 * wr4.x; ar[2][1] += h2 * wr4.y; ar[2][2] += h2 * wr4.z; ar[2][3] += h2 * wr4.w;
        }
    }

    float4 bl4 = ((const float4*)bl)[q];
    float4 br4 = ((const float4*)br)[q];
#pragma unroll
    for (int i = 0; i < 3; ++i) {
        int gn = base + ng + 16 * i;
        if (gn < NNODE) {
            int2 pk = make_int2(f2h(al[i][0] + bl4.x, al[i][1] + bl4.y),
                                f2h(al[i][2] + bl4.z, al[i][3] + bl4.w));
            ((int2*)xlh)[(size_t)gn * 16 + q] = pk;
            float4 orr = make_float4(ar[i][0] + br4.x, ar[i][1] + br4.y,
                                     ar[i][2] + br4.z, ar[i][3] + br4.w);
            ((float4*)xr)[(size_t)gn * 12 + q] = orr;
        }
    }
}

// sum within each 16-lane group (pure-VALU DPP butterfly, broadcast to all 16)
__device__ __forceinline__ float group_sum16(float v) {
#define DPP_ADD(ctrl)                                                          \
    v += __int_as_float(__builtin_amdgcn_update_dpp(                           \
        0, __float_as_int(v), ctrl, 0xf, 0xf, true))
    DPP_ADD(0xB1);    // lane ^ 1
    DPP_ADD(0x4E);    // lane ^ 2
    DPP_ADD(0x141);   // lane ^ 7
    DPP_ADD(0x140);   // lane ^ 15
#undef DPP_ADD
    return v;
}

// fused edge attention + segment softmax (fixed max=0) + aggregation.
// One wave per node; 8 edges/iteration (2 per 16-lane slot) for gather MLP.
// att-dot: a*lrelu(x) = (0.6a)x + (0.4a)|x| in TREE form — per-channel
// term = fmaf(c2,|v|, c1*v) (depth 2, 4 channels parallel) + pairwise adds
// (depth 2). R13 lesson: the 8-deep serial fma chain version stalled the
// wave (VALUBusy 82->52%); chain depth, not op count, was controlling.
// den/ac accumulators split into A/B sets (depth-1/iter), merged at end.
__global__ void aggregate_kernel(const __half* __restrict__ xlh, const float* __restrict__ xr,
                                 const int* __restrict__ starts, const int4* __restrict__ edges,
                                 const float* __restrict__ We, const float* __restrict__ att,
                                 const float* __restrict__ bias,
                                 float* __restrict__ hout) {
    int node = (blockIdx.x * blockDim.x + threadIdx.x) >> 6;
    if (node >= NNODE) return;
    const int lane = threadIdx.x & 63;
    const int g = lane >> 4;          // edge slot within chunk (0..3)
    const int r = lane & 15;          // channel quad; active if r < 12
    const bool act = r < 12;
    const int rc = act ? r : 0;

    const float4* We4 = (const float4*)We;
    float4 w0 = We4[4 * rc + 0], w1 = We4[4 * rc + 1],
           w2 = We4[4 * rc + 2], w3 = We4[4 * rc + 3];
    float4 a4 = ((const float4*)att)[rc];
    float sc = act ? L2E : 0.f;       // idle lanes contribute exactly +0
    float c1A = a4.x * (0.6f * sc), c2A = a4.x * (0.4f * sc);
    float c1B = a4.y * (0.6f * sc), c2B = a4.y * (0.4f * sc);
    float c1C = a4.z * (0.6f * sc), c2C = a4.z * (0.4f * sc);
    float c1D = a4.w * (0.6f * sc), c2D = a4.w * (0.4f * sc);
    float4 xr4 = ((const float4*)xr)[(size_t)node * 12 + rc];

    int s = starts[node];
    int e_end = starts[node + 1];
    float denA = 0.f, denB = 0.f;
    float a0A = 0.f, a1A = 0.f, a2A = 0.f, a3A = 0.f;
    float a0B = 0.f, a1B = 0.f, a2B = 0.f, a3B = 0.f;

    for (int j = s; j < e_end; j += 8) {
        int j0 = j + g, j1 = j + 4 + g;
        bool v0 = j0 < e_end, v1 = j1 < e_end;
        int4 edA = edges[v0 ? j0 : j];
        int4 edB = edges[v1 ? j1 : j];
        int2 xiA = ((const int2*)xlh)[(size_t)edA.x * 16 + rc];
        int2 xiB = ((const int2*)xlh)[(size_t)edB.x * 16 + rc];

        float2 eA01 = h2f(edA.y), eA23 = h2f(edA.z);
        float2 eB01 = h2f(edB.y), eB23 = h2f(edB.z);
        float2 xA01 = h2f(xiA.x), xA23 = h2f(xiA.y);
        float2 xB01 = h2f(xiB.x), xB23 = h2f(xiB.y);

        float vA0 = fmaf(w0.w, eA23.y, fmaf(w0.z, eA23.x, fmaf(w0.y, eA01.y, fmaf(w0.x, eA01.x, xA01.x + xr4.x))));
        float vA1 = fmaf(w1.w, eA23.y, fmaf(w1.z, eA23.x, fmaf(w1.y, eA01.y, fmaf(w1.x, eA01.x, xA01.y + xr4.y))));
        float vA2 = fmaf(w2.w, eA23.y, fmaf(w2.z, eA23.x, fmaf(w2.y, eA01.y, fmaf(w2.x, eA01.x, xA23.x + xr4.z))));
        float vA3 = fmaf(w3.w, eA23.y, fmaf(w3.z, eA23.x, fmaf(w3.y, eA01.y, fmaf(w3.x, eA01.x, xA23.y + xr4.w))));
        float vB0 = fmaf(w0.w, eB23.y, fmaf(w0.z, eB23.x, fmaf(w0.y, eB01.y, fmaf(w0.x, eB01.x, xB01.x + xr4.x))));
        float vB1 = fmaf(w1.w, eB23.y, fmaf(w1.z, eB23.x, fmaf(w1.y, eB01.y, fmaf(w1.x, eB01.x, xB01.y + xr4.y))));
        float vB2 = fmaf(w2.w, eB23.y, fmaf(w2.z, eB23.x, fmaf(w2.y, eB01.y, fmaf(w2.x, eB01.x, xB23.x + xr4.z))));
        float vB3 = fmaf(w3.w, eB23.y, fmaf(w3.z, eB23.x, fmaf(w3.y, eB01.y, fmaf(w3.x, eB01.x, xB23.y + xr4.w))));

        // tree att-dot: 4 parallel depth-2 terms, depth-2 add tree
        float tA0 = fmaf(c2A, fabsf(vA0), c1A * vA0);
        float tA1 = fmaf(c2B, fabsf(vA1), c1B * vA1);
        float tA2 = fmaf(c2C, fabsf(vA2), c1C * vA2);
        float tA3 = fmaf(c2D, fabsf(vA3), c1D * vA3);
        float tB0 = fmaf(c2A, fabsf(vB0), c1A * vB0);
        float tB1 = fmaf(c2B, fabsf(vB1), c1B * vB1);
        float tB2 = fmaf(c2C, fabsf(vB2), c1C * vB2);
        float tB3 = fmaf(c2D, fabsf(vB3), c1D * vB3);
        float tA = (tA0 + tA1) + (tA2 + tA3);
        float tB = (tB0 + tB1) + (tB2 + tB3);

        tA = group_sum16(tA);
        tB = group_sum16(tB);

        float pA = v0 ? exp2f(tA) : 0.f;
        float pB = v1 ? exp2f(tB) : 0.f;
        denA += pA;
        denB += pB;
        a0A = fmaf(pA, xA01.x, a0A);  a0B = fmaf(pB, xB01.x, a0B);
        a1A = fmaf(pA, xA01.y, a1A);  a1B = fmaf(pB, xB01.y, a1B);
        a2A = fmaf(pA, xA23.x, a2A);  a2B = fmaf(pB, xB23.x, a2B);
        a3A = fmaf(pA, xA23.y, a3A);  a3B = fmaf(pB, xB23.y, a3B);
    }

    float den = denA + denB;
    float ac0 = a0A + a0B, ac1 = a1A + a1B, ac2 = a2A + a2B, ac3 = a3A + a3B;

    // cross-group reduction: bit4 (xor16) then bit5 (xor32)
    den += __int_as_float(__builtin_amdgcn_ds_swizzle(__float_as_int(den), 0x401F));
    ac0 += __int_as_float(__builtin_amdgcn_ds_swizzle(__float_as_int(ac0), 0x401F));
    ac1 += __int_as_float(__builtin_amdgcn_ds_swizzle(__float_as_int(ac1), 0x401F));
    ac2 += __int_as_float(__builtin_amdgcn_ds_swizzle(__float_as_int(ac2), 0x401F));
    ac3 += __int_as_float(__builtin_amdgcn_ds_swizzle(__float_as_int(ac3), 0x401F));
    den += __shfl_xor(den, 32);
    ac0 += __shfl_xor(ac0, 32);
    ac1 += __shfl_xor(ac1, 32);
    ac2 += __shfl_xor(ac2, 32);
    ac3 += __shfl_xor(ac3, 32);

    if (lane < 16 && act) {
        float inv = 1.f / fmaxf(den, 1e-16f);
        float4 b4 = ((const float4*)bias)[r];
        float4 o = make_float4(fmaxf(fmaf(ac0, inv, b4.x), 0.f),
                               fmaxf(fmaf(ac1, inv, b4.y), 0.f),
                               fmaxf(fmaf(ac2, inv, b4.z), 0.f),
                               fmaxf(fmaf(ac3, inv, b4.w), 0.f));
        ((float4*)hout)[(size_t)node * 12 + r] = o;
    }
}

// ---------------- readout + head ----------------

__global__ void readout_kernel(const float* __restrict__ h, float* __restrict__ g) {
    int wid = (blockIdx.x * blockDim.x + threadIdx.x) >> 6;
    int lane = threadIdx.x & 63;
    int nw = (gridDim.x * blockDim.x) >> 6;
    if (lane < AGG) {
        float acc = 0.f;
        for (int n = wid; n < NNODE; n += nw) acc += h[n * AGG + lane];
        atomicAdd(&g[lane], acc);
    }
}

__global__ void head_kernel(const float* __restrict__ g,
                            const float* __restrict__ fc1w, const float* __restrict__ fc1b,
                            const float* __restrict__ fc2w, const float* __restrict__ fc2b,
                            float* __restrict__ out) {
    __shared__ float sg[AGG];
    __shared__ float s1[FCH];
    __shared__ float s2[NCLS];
    int t = threadIdx.x;
    if (t < AGG) sg[t] = g[t];
    __syncthreads();
    if (t < FCH) {
        float a = fc1b[t];
        for (int j = 0; j < AGG; ++j) a += fc1w[t * AGG + j] * sg[j];
        s1[t] = fmaxf(a, 0.f);
    }
    __syncthreads();
    if (t < NCLS) {
        float a = fc2b[t];
        for (int j = 0; j < FCH; ++j) a += fc2w[t * FCH + j] * s1[j];
        s2[t] = a;
    }
    __syncthreads();
    if (t == 0) {
        float mx = s2[0];
        for (int i = 1; i < NCLS; ++i) mx = fmaxf(mx, s2[i]);
        float ex[NCLS];
        float den = 0.f;
        for (int i = 0; i < NCLS; ++i) { ex[i] = __expf(s2[i] - mx); den += ex[i]; }
        for (int i = 0; i < NCLS; ++i) out[i] = ex[i] / den;
    }
}

// ---------------- launch ----------------

extern "C" void kernel_launch(void* const* d_in, const int* in_sizes, int n_in,
                              void* d_out, int out_size, void* d_ws, size_t ws_size,
                              hipStream_t stream) {
    const float* x  = (const float*)d_in[0];
    const int*   ei = (const int*)d_in[1];
    const float* ea = (const float*)d_in[2];
    const float* Wl[3], *bl[3], *Wr[3], *br[3], *We[3], *att[3], *bb[3];
    for (int l = 0; l < 3; ++l) {
        int base = 3 + l * 7;
        Wl[l]  = (const float*)d_in[base + 0];
        bl[l]  = (const float*)d_in[base + 1];
        Wr[l]  = (const float*)d_in[base + 2];
        br[l]  = (const float*)d_in[base + 3];
        We[l]  = (const float*)d_in[base + 4];
        att[l] = (const float*)d_in[base + 5];
        bb[l]  = (const float*)d_in[base + 6];
    }
    const float* fc1w = (const float*)d_in[24];
    const float* fc1b = (const float*)d_in[25];
    const float* fc2w = (const float*)d_in[26];
    const float* fc2b = (const float*)d_in[27];
    float* outp = (float*)d_out;

    char* ws = (char*)d_ws;
    // region0 (32.0 MB): xlh (12.8 MB) + xr (19.2 MB); ALIASED by bbuf
    // (31.3 MB) whose lifetime (binA->binB) ends before transform writes.
    __half* xlh   = (__half*)ws;
    float*  xr    = (float*)(ws + (size_t)NNODE * 64 * 2);
    int4*   bbuf  = (int4*)ws;
    size_t off = (size_t)NNODE * 64 * 2 + (size_t)NNODE * AGG * 4;
    auto take = [&](size_t bytes) -> void* {
        void* p = ws + off;
        off = (off + bytes + 255) & ~(size_t)255;
        return p;
    };
    float*  h      = (float*)take((size_t)NNODE * AGG * 4);
    int*    starts = (int*)take((size_t)(NNODE + 1) * 4);
    int*    bcnt   = (int*)take(NBUCK * 4);
    int*    bstart = (int*)take((NBUCK + 1) * 4);
    int4*   edges  = (int4*)take((size_t)NEDGE * 16);
    float*  g      = (float*)take(64 * 4);

    // CSR build: binA (bucket bins) -> bucket scan -> binB (per-node count +
    // starts + exact CSR scatter)
    hipMemsetAsync(bcnt, 0, NBUCK * 4, stream);
    binA_kernel<<<(NEDGE + EPB - 1) / EPB, 256, 0, stream>>>(ei, (const float4*)ea,
                                                             bcnt, bbuf);
    bscan_kernel<<<1, 512, 0, stream>>>(bcnt, bstart, starts);
    binB_kernel<<<NBUCK, 1024, 0, stream>>>(bcnt, bstart, bbuf, starts, edges);

    const int TGRID = (NNODE + 47) / 48;
    const int AGRID = (NNODE + 3) / 4;

    transform_tiled<FIN, 64><<<TGRID, 192, 0, stream>>>(x, Wl[0], bl[0], Wr[0], br[0], xlh, xr);
    aggregate_kernel<<<AGRID, 256, 0, stream>>>(xlh, xr, starts, edges,
                                                We[0], att[0], bb[0], h);
    transform_tiled<AGG, 48><<<TGRID, 192, 0, stream>>>(h, Wl[1], bl[1], Wr[1], br[1], xlh, xr);
    aggregate_kernel<<<AGRID, 256, 0, stream>>>(xlh, xr, starts, edges,
                                                We[1], att[1], bb[1], h);
    transform_tiled<AGG, 48><<<TGRID, 192, 0, stream>>>(h, Wl[2], bl[2], Wr[2], br[2], xlh, xr);
    aggregate_kernel<<<AGRID, 256, 0, stream>>>(xlh, xr, starts, edges,
                                                We[2], att[2], bb[2], h);

    hipMemsetAsync(g, 0, 64 * 4, stream);
    readout_kernel<<<256, 256, 0, stream>>>(h, g);
    head_kernel<<<1, 192, 0, stream>>>(g, fc1w, fc1b, fc2w, fc2b, outp);
}

// Round 15
// 416.748 us; speedup vs baseline: 1.2506x; 1.0289x over previous
//
#include <hip/hip_runtime.h>
#include <hip/hip_fp16.h>
#include <math.h>

#define NNODE 100000
#define NEDGE 1600000
#define FIN   128
#define AGG   48
#define FCH   192
#define NCLS  10
#define SLOPE 0.2f
#define L2E   1.44269504088896340736f

#define NBUCK 391     // ceil(NNODE/256) coarse dst-buckets (256 nodes each)
#define BCAP  4992    // bucket capacity: mean 4096, sigma 64 -> +14 sigma
#define EPB   2048    // edges per binA block

// fp16 pack/unpack helpers
__device__ __forceinline__ float2 h2f(int p) {
    union { int i; __half2 h; } u; u.i = p;
    return __half22float2(u.h);
}
__device__ __forceinline__ int f2h(float a, float b) {
    union { __half2 h; int i; } u;
    u.h = __floats2half2_rn(a, b);
    return u.i;
}

// ---------------- CSR build (two-level counting sort, no node histogram) ----

// Pass A, LDS-staged: bin 2048 edges into coarse buckets; records staged in
// LDS grouped by bucket, written out linearly (coalesced runs). No per-node
// atomics (R8: 1.6M atomics into 400KB was a ~100us wall).
__global__ __launch_bounds__(256) void binA_kernel(const int* __restrict__ ei,
                                                   const float4* __restrict__ ea,
                                                   int* __restrict__ bcnt,
                                                   int4* __restrict__ bbuf) {
    __shared__ int  hist[NBUCK];
    __shared__ int  lofs[NBUCK];     // exclusive scan of hist (block-local)
    __shared__ int  gbase[NBUCK];    // reserved global base within bucket
    __shared__ int  scA[512], scB[512];
    __shared__ int  gidx[EPB];       // per-slot global bbuf index (-1 = drop)
    __shared__ int4 stage[EPB];

    const int t = threadIdx.x;
    const int wgbase = blockIdx.x * EPB;
    const int nvalid = min(EPB, NEDGE - wgbase);

    for (int i = t; i < NBUCK; i += 256) hist[i] = 0;
    __syncthreads();

    int d[8], rank[8];
#pragma unroll
    for (int i = 0; i < 8; ++i) {
        int e = wgbase + i * 256 + t;
        if (e < NEDGE) {
            d[i] = ei[NEDGE + e];
            rank[i] = atomicAdd(&hist[d[i] >> 8], 1);
        } else d[i] = -1;
    }
    __syncthreads();

    // Hillis-Steele inclusive scan of hist (padded to 512), ping-pong A->B
    {
        scA[t] = (t < NBUCK) ? hist[t] : 0;
        scA[t + 256] = (t + 256 < NBUCK) ? hist[t + 256] : 0;
        __syncthreads();
        int* src = scA; int* dst = scB;
#pragma unroll
        for (int o = 1; o < 512; o <<= 1) {
            int i0 = t, i1 = t + 256;
            int v0 = src[i0] + ((i0 >= o) ? src[i0 - o] : 0);
            int v1 = src[i1] + ((i1 >= o) ? src[i1 - o] : 0);
            __syncthreads();
            dst[i0] = v0; dst[i1] = v1;
            __syncthreads();
            int* tmp = src; src = dst; dst = tmp;
        }
        if (t < NBUCK) lofs[t] = src[t] - hist[t];
        if (t + 256 < NBUCK) lofs[t + 256] = src[t + 256] - hist[t + 256];
    }
    for (int i = t; i < NBUCK; i += 256)
        gbase[i] = hist[i] ? atomicAdd(&bcnt[i], hist[i]) : 0;
    __syncthreads();

#pragma unroll
    for (int i = 0; i < 8; ++i) {
        int e = wgbase + i * 256 + t;
        if (e < NEDGE) {
            int b = d[i] >> 8;
            int slot = lofs[b] + rank[i];
            int gp = gbase[b] + rank[i];
            float4 v = ea[e];
            stage[slot] = make_int4(ei[e], d[i], f2h(v.x, v.y), f2h(v.z, v.w));
            gidx[slot] = (gp < BCAP) ? (b * BCAP + gp) : -1;
        }
    }
    __syncthreads();

    for (int i = t; i < nvalid; i += 256) {
        int gi = gidx[i];
        if (gi >= 0) bbuf[gi] = stage[i];
    }
}

// exclusive scan of the 391 bucket totals (single block)
__global__ void bscan_kernel(const int* __restrict__ bcnt, int* __restrict__ bstart,
                             int* __restrict__ starts) {
    __shared__ int s[512];
    int t = threadIdx.x;
    int v = (t < NBUCK) ? bcnt[t] : 0;
    s[t] = v;
    __syncthreads();
    int acc = v;
    for (int o = 1; o < 512; o <<= 1) {
        int x = (t >= o) ? s[t - o] : 0;
        __syncthreads();
        acc += x;
        s[t] = acc;
        __syncthreads();
    }
    if (t < NBUCK) bstart[t] = acc - v;
    if (t == 0) starts[NNODE] = NEDGE;
}

// Pass B: one workgroup (1024 threads) per coarse bucket; per-node LDS count
// + scan -> starts[]; exact-slot scatter into the bucket's contiguous span.
__global__ __launch_bounds__(1024) void binB_kernel(const int* __restrict__ bcnt,
                                                    const int* __restrict__ bstart,
                                                    const int4* __restrict__ bbuf,
                                                    int* __restrict__ starts,
                                                    int4* __restrict__ edges) {
    __shared__ int ncnt[256];
    __shared__ int sc[256];
    __shared__ int lcur[256];
    const int b = blockIdx.x;
    const int t = threadIdx.x;
    if (t < 256) ncnt[t] = 0;
    __syncthreads();
    int cnt = min(bcnt[b], BCAP);
    int base = bstart[b];
    for (int i = t; i < cnt; i += 1024)
        atomicAdd(&ncnt[bbuf[(size_t)b * BCAP + i].y & 255], 1);
    __syncthreads();
    int v = 0, acc = 0;
    if (t < 256) { v = ncnt[t]; sc[t] = v; }
    __syncthreads();
    acc = v;
    for (int o = 1; o < 256; o <<= 1) {
        int x = 0;
        if (t < 256 && t >= o) x = sc[t - o];
        __syncthreads();
        if (t < 256) { acc += x; sc[t] = acc; }
        __syncthreads();
    }
    if (t < 256) {
        int node = (b << 8) + t;
        int st = base + acc - v;      // exclusive
        lcur[t] = st;
        if (node < NNODE) starts[node] = st;
    }
    __syncthreads();
    for (int i = t; i < cnt; i += 1024) {
        int4 rec = bbuf[(size_t)b * BCAP + i];
        int pos = atomicAdd(&lcur[rec.y & 255], 1);
        edges[pos] = make_int4(rec.x, rec.z, rec.w, 0);
    }
}

// ---------------- per-layer kernels ----------------

// LDS-tiled dual GEMM, conflict-free layouts (R9 fix). xl written packed
// fp16, row padded to 64 halfs (128B) -> one cache line per gather; xr fp32.
template <int K, int KT>
__global__ __launch_bounds__(192) void transform_tiled(
    const float* __restrict__ h,
    const float* __restrict__ Wl, const float* __restrict__ bl,
    const float* __restrict__ Wr, const float* __restrict__ br,
    __half* __restrict__ xlh, float* __restrict__ xr)
{
    constexpr int NT = 48;
    constexpr int KP = K + 4;
    __shared__ float sW[2][KT * 48];     // [m][j*48+k] = W^T tile
    __shared__ float sH[NT * KP];

    const int t = threadIdx.x;
    const int base = blockIdx.x * NT;

    for (int p = t; p < NT * (K / 4); p += 192) {
        int row = p / (K / 4);
        int c4  = p - row * (K / 4);
        int gn  = base + row;
        float4 v = (gn < NNODE) ? ((const float4*)h)[(size_t)gn * (K / 4) + c4]
                                : make_float4(0.f, 0.f, 0.f, 0.f);
        ((float4*)(sH + row * KP))[c4] = v;
    }

    const int q  = t % 12;
    const int ng = t / 12;
    float al[3][4] = {};
    float ar[3][4] = {};

    const float4* Wl4 = (const float4*)Wl;
    const float4* Wr4 = (const float4*)Wr;

    for (int j0 = 0; j0 < K; j0 += KT) {
        __syncthreads();
        for (int p = t; p < 48 * (KT / 4); p += 192) {
            int k  = p % 48;
            int jq = p / 48;
            float4 wl = Wl4[(size_t)k * (K / 4) + (j0 / 4) + jq];
            float4 wr = Wr4[(size_t)k * (K / 4) + (j0 / 4) + jq];
            int j = jq * 4;
            sW[0][(j + 0) * 48 + k] = wl.x; sW[0][(j + 1) * 48 + k] = wl.y;
            sW[0][(j + 2) * 48 + k] = wl.z; sW[0][(j + 3) * 48 + k] = wl.w;
            sW[1][(j + 0) * 48 + k] = wr.x; sW[1][(j + 1) * 48 + k] = wr.y;
            sW[1][(j + 2) * 48 + k] = wr.z; sW[1][(j + 3) * 48 + k] = wr.w;
        }
        __syncthreads();

        const float4* sWl4 = (const float4*)sW[0];
        const float4* sWr4 = (const float4*)sW[1];
        const float* sHj = sH + j0;
#pragma unroll 4
        for (int j = 0; j < KT; ++j) {
            float4 wl4 = sWl4[j * 12 + q];
            float4 wr4 = sWr4[j * 12 + q];
            float h0 = sHj[(ng + 0)  * KP + j];
            float h1 = sHj[(ng + 16) * KP + j];
            float h2 = sHj[(ng + 32) * KP + j];
            al[0][0] += h0 * wl4.x; al[0][1] += h0 * wl4.y; al[0][2] += h0 * wl4.z; al[0][3] += h0 * wl4.w;
            ar[0][0] += h0 * wr4.x; ar[0][1] += h0 * wr4.y; ar[0][2] += h0 * wr4.z; ar[0][3] += h0 * wr4.w;
            al[1][0] += h1 * wl4.x; al[1][1] += h1 * wl4.y; al[1][2] += h1 * wl4.z; al[1][3] += h1 * wl4.w;
            ar[1][0] += h1 * wr4.x; ar[1][1] += h1 * wr4.y; ar[1][2] += h1 * wr4.z; ar[1][3] += h1 * wr4.w;
            al[2][0] += h2 * wl4.x; al[2][1] += h2 * wl4.y; al[2][2] += h2 * wl4.z; al[2][3] += h2 * wl4.w;
            ar[2][0] += h2 * wr4.x; ar[2][1] += h2 * wr4.y; ar[2][2] += h2 * wr4.z; ar[2][3] += h2 * wr4.w;
        }
    }

    float4 bl4 = ((const float4*)bl)[q];
    float4 br4 = ((const float4*)br)[q];
#pragma unroll
    for (int i = 0; i < 3; ++i) {
        int gn = base + ng + 16 * i;
        if (gn < NNODE) {
            int2 pk = make_int2(f2h(al[i][0] + bl4.x, al[i][1] + bl4.y),
                                f2h(al[i][2] + bl4.z, al[i][3] + bl4.w));
            ((int2*)xlh)[(size_t)gn * 16 + q] = pk;
            float4 orr = make_float4(ar[i][0] + br4.x, ar[i][1] + br4.y,
                                     ar[i][2] + br4.z, ar[i][3] + br4.w);
            ((float4*)xr)[(size_t)gn * 12 + q] = orr;
        }
    }
}

// sum within each 16-lane group (pure-VALU DPP butterfly, broadcast to all 16)
__device__ __forceinline__ float group_sum16(float v) {
#define DPP_ADD(ctrl)                                                          \
    v += __int_as_float(__builtin_amdgcn_update_dpp(                           \
        0, __float_as_int(v), ctrl, 0xf, 0xf, true))
    DPP_ADD(0xB1);    // lane ^ 1
    DPP_ADD(0x4E);    // lane ^ 2
    DPP_ADD(0x141);   // lane ^ 7
    DPP_ADD(0x140);   // lane ^ 15
#undef DPP_ADD
    return v;
}

// fused edge attention + segment softmax (fixed max=0) + aggregation.
// One wave per node; 8 edges per iteration (2 per 16-lane slot) -> two
// independent gathers in flight per lane (latency-bound gather MLP).
// R10-proven configuration: fp32 edge math, fp16 xl gather, fp32 xr.
// (R12 packed-fp16, R13 chained-identity, R14 tree-identity all failed to
// beat this form — issue/latency/occupancy balance point.)
__global__ void aggregate_kernel(const __half* __restrict__ xlh, const float* __restrict__ xr,
                                 const int* __restrict__ starts, const int4* __restrict__ edges,
                                 const float* __restrict__ We, const float* __restrict__ att,
                                 const float* __restrict__ bias,
                                 float* __restrict__ hout) {
    int node = (blockIdx.x * blockDim.x + threadIdx.x) >> 6;
    if (node >= NNODE) return;
    const int lane = threadIdx.x & 63;
    const int g = lane >> 4;          // edge slot within chunk (0..3)
    const int r = lane & 15;          // channel quad; active if r < 12
    const bool act = r < 12;
    const int rc = act ? r : 0;
    const int c0 = 4 * rc;

    const float4* We4 = (const float4*)We;
    float4 w0 = We4[4 * rc + 0], w1 = We4[4 * rc + 1],
           w2 = We4[4 * rc + 2], w3 = We4[4 * rc + 3];
    float4 a4 = ((const float4*)att)[rc];
    float aA = act ? a4.x * L2E : 0.f;
    float aB = act ? a4.y * L2E : 0.f;
    float aC = act ? a4.z * L2E : 0.f;
    float aD = act ? a4.w * L2E : 0.f;
    float4 xr4 = ((const float4*)xr)[(size_t)node * 12 + rc];

    int s = starts[node];
    int e_end = starts[node + 1];
    float den = 0.f, ac0 = 0.f, ac1 = 0.f, ac2 = 0.f, ac3 = 0.f;

    for (int j = s; j < e_end; j += 8) {
        int j0 = j + g, j1 = j + 4 + g;
        bool v0 = j0 < e_end, v1 = j1 < e_end;
        int4 edA = edges[v0 ? j0 : j];
        int4 edB = edges[v1 ? j1 : j];
        int2 xiA = ((const int2*)xlh)[(size_t)edA.x * 16 + rc];
        int2 xiB = ((const int2*)xlh)[(size_t)edB.x * 16 + rc];

        float2 eA01 = h2f(edA.y), eA23 = h2f(edA.z);
        float2 eB01 = h2f(edB.y), eB23 = h2f(edB.z);
        float2 xA01 = h2f(xiA.x), xA23 = h2f(xiA.y);
        float2 xB01 = h2f(xiB.x), xB23 = h2f(xiB.y);

        float vA0 = fmaf(w0.w, eA23.y, fmaf(w0.z, eA23.x, fmaf(w0.y, eA01.y, fmaf(w0.x, eA01.x, xA01.x + xr4.x))));
        float vA1 = fmaf(w1.w, eA23.y, fmaf(w1.z, eA23.x, fmaf(w1.y, eA01.y, fmaf(w1.x, eA01.x, xA01.y + xr4.y))));
        float vA2 = fmaf(w2.w, eA23.y, fmaf(w2.z, eA23.x, fmaf(w2.y, eA01.y, fmaf(w2.x, eA01.x, xA23.x + xr4.z))));
        float vA3 = fmaf(w3.w, eA23.y, fmaf(w3.z, eA23.x, fmaf(w3.y, eA01.y, fmaf(w3.x, eA01.x, xA23.y + xr4.w))));
        float vB0 = fmaf(w0.w, eB23.y, fmaf(w0.z, eB23.x, fmaf(w0.y, eB01.y, fmaf(w0.x, eB01.x, xB01.x + xr4.x))));
        float vB1 = fmaf(w1.w, eB23.y, fmaf(w1.z, eB23.x, fmaf(w1.y, eB01.y, fmaf(w1.x, eB01.x, xB01.y + xr4.y))));
        float vB2 = fmaf(w2.w, eB23.y, fmaf(w2.z, eB23.x, fmaf(w2.y, eB01.y, fmaf(w2.x, eB01.x, xB23.x + xr4.z))));
        float vB3 = fmaf(w3.w, eB23.y, fmaf(w3.z, eB23.x, fmaf(w3.y, eB01.y, fmaf(w3.x, eB01.x, xB23.y + xr4.w))));

        float tA, tB;
        tA =           aA * fmaf(SLOPE, fminf(vA0, 0.f), fmaxf(vA0, 0.f));
        tA = fmaf(aB, fmaf(SLOPE, fminf(vA1, 0.f), fmaxf(vA1, 0.f)), tA);
        tA = fmaf(aC, fmaf(SLOPE, fminf(vA2, 0.f), fmaxf(vA2, 0.f)), tA);
        tA = fmaf(aD, fmaf(SLOPE, fminf(vA3, 0.f), fmaxf(vA3, 0.f)), tA);
        tB =           aA * fmaf(SLOPE, fminf(vB0, 0.f), fmaxf(vB0, 0.f));
        tB = fmaf(aB, fmaf(SLOPE, fminf(vB1, 0.f), fmaxf(vB1, 0.f)), tB);
        tB = fmaf(aC, fmaf(SLOPE, fminf(vB2, 0.f), fmaxf(vB2, 0.f)), tB);
        tB = fmaf(aD, fmaf(SLOPE, fminf(vB3, 0.f), fmaxf(vB3, 0.f)), tB);

        tA = group_sum16(tA);
        tB = group_sum16(tB);

        float pA = v0 ? exp2f(tA) : 0.f;
        float pB = v1 ? exp2f(tB) : 0.f;
        den += pA + pB;
        ac0 = fmaf(pB, xB01.x, fmaf(pA, xA01.x, ac0));
        ac1 = fmaf(pB, xB01.y, fmaf(pA, xA01.y, ac1));
        ac2 = fmaf(pB, xB23.x, fmaf(pA, xA23.x, ac2));
        ac3 = fmaf(pB, xB23.y, fmaf(pA, xA23.y, ac3));
    }

    // cross-group reduction: bit4 (xor16) then bit5 (xor32)
    den += __int_as_float(__builtin_amdgcn_ds_swizzle(__float_as_int(den), 0x401F));
    ac0 += __int_as_float(__builtin_amdgcn_ds_swizzle(__float_as_int(ac0), 0x401F));
    ac1 += __int_as_float(__builtin_amdgcn_ds_swizzle(__float_as_int(ac1), 0x401F));
    ac2 += __int_as_float(__builtin_amdgcn_ds_swizzle(__float_as_int(ac2), 0x401F));
    ac3 += __int_as_float(__builtin_amdgcn_ds_swizzle(__float_as_int(ac3), 0x401F));
    den += __shfl_xor(den, 32);
    ac0 += __shfl_xor(ac0, 32);
    ac1 += __shfl_xor(ac1, 32);
    ac2 += __shfl_xor(ac2, 32);
    ac3 += __shfl_xor(ac3, 32);

    if (lane < 16 && act) {
        float inv = 1.f / fmaxf(den, 1e-16f);
        float4 b4 = ((const float4*)bias)[r];
        float4 o = make_float4(fmaxf(fmaf(ac0, inv, b4.x), 0.f),
                               fmaxf(fmaf(ac1, inv, b4.y), 0.f),
                               fmaxf(fmaf(ac2, inv, b4.z), 0.f),
                               fmaxf(fmaf(ac3, inv, b4.w), 0.f));
        ((float4*)hout)[(size_t)node * 12 + r] = o;
    }
}

// ---------------- readout + head ----------------

__global__ void readout_kernel(const float* __restrict__ h, float* __restrict__ g) {
    int wid = (blockIdx.x * blockDim.x + threadIdx.x) >> 6;
    int lane = threadIdx.x & 63;
    int nw = (gridDim.x * blockDim.x) >> 6;
    if (lane < AGG) {
        float acc = 0.f;
        for (int n = wid; n < NNODE; n += nw) acc += h[n * AGG + lane];
        atomicAdd(&g[lane], acc);
    }
}

__global__ void head_kernel(const float* __restrict__ g,
                            const float* __restrict__ fc1w, const float* __restrict__ fc1b,
                            const float* __restrict__ fc2w, const float* __restrict__ fc2b,
                            float* __restrict__ out) {
    __shared__ float sg[AGG];
    __shared__ float s1[FCH];
    __shared__ float s2[NCLS];
    int t = threadIdx.x;
    if (t < AGG) sg[t] = g[t];
    __syncthreads();
    if (t < FCH) {
        float a = fc1b[t];
        for (int j = 0; j < AGG; ++j) a += fc1w[t * AGG + j] * sg[j];
        s1[t] = fmaxf(a, 0.f);
    }
    __syncthreads();
    if (t < NCLS) {
        float a = fc2b[t];
        for (int j = 0; j < FCH; ++j) a += fc2w[t * FCH + j] * s1[j];
        s2[t] = a;
    }
    __syncthreads();
    if (t == 0) {
        float mx = s2[0];
        for (int i = 1; i < NCLS; ++i) mx = fmaxf(mx, s2[i]);
        float ex[NCLS];
        float den = 0.f;
        for (int i = 0; i < NCLS; ++i) { ex[i] = __expf(s2[i] - mx); den += ex[i]; }
        for (int i = 0; i < NCLS; ++i) out[i] = ex[i] / den;
    }
}

// ---------------- launch ----------------

extern "C" void kernel_launch(void* const* d_in, const int* in_sizes, int n_in,
                              void* d_out, int out_size, void* d_ws, size_t ws_size,
                              hipStream_t stream) {
    const float* x  = (const float*)d_in[0];
    const int*   ei = (const int*)d_in[1];
    const float* ea = (const float*)d_in[2];
    const float* Wl[3], *bl[3], *Wr[3], *br[3], *We[3], *att[3], *bb[3];
    for (int l = 0; l < 3; ++l) {
        int base = 3 + l * 7;
        Wl[l]  = (const float*)d_in[base + 0];
        bl[l]  = (const float*)d_in[base + 1];
        Wr[l]  = (const float*)d_in[base + 2];
        br[l]  = (const float*)d_in[base + 3];
        We[l]  = (const float*)d_in[base + 4];
        att[l] = (const float*)d_in[base + 5];
        bb[l]  = (const float*)d_in[base + 6];
    }
    const float* fc1w = (const float*)d_in[24];
    const float* fc1b = (const float*)d_in[25];
    const float* fc2w = (const float*)d_in[26];
    const float* fc2b = (const float*)d_in[27];
    float* outp = (float*)d_out;

    char* ws = (char*)d_ws;
    // region0 (32.0 MB): xlh (12.8 MB) + xr (19.2 MB); ALIASED by bbuf
    // (31.3 MB) whose lifetime (binA->binB) ends before transform writes.
    __half* xlh   = (__half*)ws;
    float*  xr    = (float*)(ws + (size_t)NNODE * 64 * 2);
    int4*   bbuf  = (int4*)ws;
    size_t off = (size_t)NNODE * 64 * 2 + (size_t)NNODE * AGG * 4;
    auto take = [&](size_t bytes) -> void* {
        void* p = ws + off;
        off = (off + bytes + 255) & ~(size_t)255;
        return p;
    };
    float*  h      = (float*)take((size_t)NNODE * AGG * 4);
    int*    starts = (int*)take((size_t)(NNODE + 1) * 4);
    int*    bcnt   = (int*)take(NBUCK * 4);
    int*    bstart = (int*)take((NBUCK + 1) * 4);
    int4*   edges  = (int4*)take((size_t)NEDGE * 16);
    float*  g      = (float*)take(64 * 4);

    // CSR build: binA (bucket bins) -> bucket scan -> binB (per-node count +
    // starts + exact CSR scatter)
    hipMemsetAsync(bcnt, 0, NBUCK * 4, stream);
    binA_kernel<<<(NEDGE + EPB - 1) / EPB, 256, 0, stream>>>(ei, (const float4*)ea,
                                                             bcnt, bbuf);
    bscan_kernel<<<1, 512, 0, stream>>>(bcnt, bstart, starts);
    binB_kernel<<<NBUCK, 1024, 0, stream>>>(bcnt, bstart, bbuf, starts, edges);

    const int TGRID = (NNODE + 47) / 48;
    const int AGRID = (NNODE + 3) / 4;

    transform_tiled<FIN, 64><<<TGRID, 192, 0, stream>>>(x, Wl[0], bl[0], Wr[0], br[0], xlh, xr);
    aggregate_kernel<<<AGRID, 256, 0, stream>>>(xlh, xr, starts, edges,
                                                We[0], att[0], bb[0], h);
    transform_tiled<AGG, 48><<<TGRID, 192, 0, stream>>>(h, Wl[1], bl[1], Wr[1], br[1], xlh, xr);
    aggregate_kernel<<<AGRID, 256, 0, stream>>>(xlh, xr, starts, edges,
                                                We[1], att[1], bb[1], h);
    transform_tiled<AGG, 48><<<TGRID, 192, 0, stream>>>(h, Wl[2], bl[2], Wr[2], br[2], xlh, xr);
    aggregate_kernel<<<AGRID, 256, 0, stream>>>(xlh, xr, starts, edges,
                                                We[2], att[2], bb[2], h);

    hipMemsetAsync(g, 0, 64 * 4, stream);
    readout_kernel<<<256, 256, 0, stream>>>(h, g);
    head_kernel<<<1, 192, 0, stream>>>(g, fc1w, fc1b, fc2w, fc2b, outp);
}